// Round 3
// baseline (679.668 us; speedup 1.0000x reference)
//
#include <hip/hip_runtime.h>

#define B_ 4
#define C_ 512
#define CI_ 256
#define N_ 4096
#define SCALE_PAM 0.04419417382415922f  // 1/sqrt(512)
#define SCALE_CAM (1.0f/64.0f)          // 1/sqrt(4096)
#define SHIFT_PAM 8.0f                  // fixed softmax shift (logits bounded ~|8|)

typedef float v4f __attribute__((ext_vector_type(4)));
typedef short v8s __attribute__((ext_vector_type(8)));

__device__ __forceinline__ unsigned short f2bf(float f) {
  unsigned int u = __float_as_uint(f);
  u = (u + 0x7FFFu + ((u >> 16) & 1u)) >> 16;
  return (unsigned short)u;
}
__device__ __forceinline__ float bf2f(unsigned short s) {
  return __uint_as_float(((unsigned int)s) << 16);
}
__device__ __forceinline__ v8s ld8(const unsigned short* p) {
  v8s r; *(int4*)&r = *(const int4*)p; return r;
}
__device__ __forceinline__ v4f mfma16(v8s a, v8s b, v4f c) {
  return __builtin_amdgcn_mfma_f32_16x16x32_bf16(a, b, c, 0, 0, 0);
}

// ---------------------------------------------------------------------------
// K0a: transpose+convert x fp32 [b][c][n] -> xT bf16 [b][n][c]. 64x64 tiles.
// ---------------------------------------------------------------------------
__global__ __launch_bounds__(256) void k_xT(const float* __restrict__ x,
                                            unsigned short* __restrict__ xT) {
  const int b = blockIdx.z, c0 = blockIdx.y * 64, n0 = blockIdx.x * 64;
  const int t = threadIdx.x;
  __shared__ unsigned short ts[64 * 72];  // [n][c]
  const int cl = t >> 2, nseg = (t & 3) * 16;
  const float* xr = x + ((size_t)b * C_ + c0 + cl) * N_ + n0 + nseg;
#pragma unroll
  for (int k = 0; k < 4; ++k) {
    float4 f = *(const float4*)(xr + k * 4);
    ts[(nseg + k * 4 + 0) * 72 + cl] = f2bf(f.x);
    ts[(nseg + k * 4 + 1) * 72 + cl] = f2bf(f.y);
    ts[(nseg + k * 4 + 2) * 72 + cl] = f2bf(f.z);
    ts[(nseg + k * 4 + 3) * 72 + cl] = f2bf(f.w);
  }
  __syncthreads();
  const int nl = t >> 2, cseg = (t & 3) * 16;
  int4 a0 = *(int4*)&ts[nl * 72 + cseg];
  int4 a1 = *(int4*)&ts[nl * 72 + cseg + 8];
  unsigned short* dst = xT + ((size_t)b * N_ + n0 + nl) * C_ + c0 + cseg;
  *(int4*)dst = a0; *(int4*)(dst + 8) = a1;
}

// ---------------------------------------------------------------------------
// K0b: convert wq/wk/wv fp32 -> wb bf16 [1024][512]
// ---------------------------------------------------------------------------
__global__ __launch_bounds__(256) void k_wb(const float* __restrict__ wq,
                                            const float* __restrict__ wk,
                                            const float* __restrict__ wv,
                                            unsigned short* __restrict__ wb) {
  int e = (blockIdx.x * 256 + threadIdx.x) * 4;
  int row = e >> 9, col = e & 511;
  const float* src = (row < 256) ? &wq[row * 512 + col]
                   : (row < 512) ? &wk[(row - 256) * 512 + col]
                                 : &wv[(row - 512) * 512 + col];
  float4 f = *(const float4*)src;
  ushort4 o = { f2bf(f.x), f2bf(f.y), f2bf(f.z), f2bf(f.w) };
  *(ushort4*)&wb[e] = o;
}

// ---------------------------------------------------------------------------
// K1: QKV conv via MFMA, 128o x 128n tile, 512 thr (8 waves, 2x4).
// A = wb [o][c] frags, B = xT [n][c] frags.
// q/k written transposed (qT/kT [n][o]) via LDS; v natural [c][n] bf16.
// ---------------------------------------------------------------------------
__global__ __launch_bounds__(512, 4) void k_qkv(
    const unsigned short* __restrict__ wb, const unsigned short* __restrict__ xT,
    const float* __restrict__ bq, const float* __restrict__ bk, const float* __restrict__ bv,
    unsigned short* __restrict__ qT, unsigned short* __restrict__ kT,
    unsigned short* __restrict__ vbf) {
  const int b = blockIdx.z, o0 = blockIdx.y * 128, n0 = blockIdx.x * 128;
  const int t = threadIdx.x, wave = t >> 6, lane = t & 63;
  const int la = lane & 15, quad = lane >> 4;
  const int ow = wave & 1, nw = wave >> 1;
  const unsigned short* xTb = xT + (size_t)b * N_ * C_;
  __shared__ unsigned short tp[128 * 136];

  v4f acc[4][2];
#pragma unroll
  for (int i = 0; i < 4; ++i)
#pragma unroll
    for (int j = 0; j < 2; ++j) acc[i][j] = (v4f){0.f, 0.f, 0.f, 0.f};

  unsigned ar[4], br[2];
#pragma unroll
  for (int oi = 0; oi < 4; ++oi) ar[oi] = (unsigned)(o0 + ow * 64 + oi * 16 + la) * 512u;
#pragma unroll
  for (int nj = 0; nj < 2; ++nj) br[nj] = (unsigned)(n0 + nw * 32 + nj * 16 + la) * 512u;

#pragma unroll 4
  for (int s = 0; s < 16; ++s) {
    const int kof = s * 32 + quad * 8;
    v8s b0 = ld8(&xTb[br[0] + kof]);
    v8s b1 = ld8(&xTb[br[1] + kof]);
#pragma unroll
    for (int oi = 0; oi < 4; ++oi) {
      v8s a = ld8(&wb[ar[oi] + kof]);
      acc[oi][0] = mfma16(a, b0, acc[oi][0]);
      acc[oi][1] = mfma16(a, b1, acc[oi][1]);
    }
  }

  if (o0 >= 512) {
#pragma unroll
    for (int oi = 0; oi < 4; ++oi)
#pragma unroll
      for (int nj = 0; nj < 2; ++nj)
#pragma unroll
        for (int r = 0; r < 4; ++r) {
          int og = o0 - 512 + ow * 64 + oi * 16 + quad * 4 + r;
          int ng = n0 + nw * 32 + nj * 16 + la;
          vbf[((size_t)b * C_ + og) * N_ + ng] = f2bf(acc[oi][nj][r] + bv[og]);
        }
  } else {
    const float* bias = (o0 < 256) ? bq : bk;
#pragma unroll
    for (int oi = 0; oi < 4; ++oi)
#pragma unroll
      for (int nj = 0; nj < 2; ++nj)
#pragma unroll
        for (int r = 0; r < 4; ++r) {
          int ol = ow * 64 + oi * 16 + quad * 4 + r;
          int nl = nw * 32 + nj * 16 + la;
          tp[nl * 136 + ol] = f2bf(acc[oi][nj][r] + bias[(o0 & 255) + ol]);
        }
    __syncthreads();
    const int nl = t >> 2;
    unsigned short* dstb = ((o0 < 256) ? qT : kT)
        + ((size_t)b * N_ + n0 + nl) * CI_ + (o0 & 255);
#pragma unroll
    for (int chunk = 0; chunk < 4; ++chunk) {
      int oseg = chunk * 32 + (t & 3) * 8;
      *(int4*)&dstb[oseg] = *(int4*)&tp[nl * 136 + oseg];
    }
  }
}

// ---------------------------------------------------------------------------
// K2: fused PAM, fixed-shift flash. 1024 thr (16 waves), i-tile 64, j-tile 64.
// S-phase: wave w -> S-subtile (iw=w&3, jw=w>>2). PV: wave w -> c in [w*32,+32).
// One barrier per j-iter (double-buffered P). Epilogue: sa=tanh(gp*pam+x),
// writes sabf [c][n] + saT [n][c] (LDS-staged, rotation swizzle), both bf16.
// ---------------------------------------------------------------------------
__global__ __launch_bounds__(1024, 4) void k_pam(
    const unsigned short* __restrict__ qT, const unsigned short* __restrict__ kT,
    const unsigned short* __restrict__ vbf, const float* __restrict__ x,
    const float* __restrict__ gamma_pam,
    unsigned short* __restrict__ sabf, unsigned short* __restrict__ saT) {
  const int b = blockIdx.y, i0 = blockIdx.x * 64;
  const int t = threadIdx.x, wave = t >> 6, lane = t & 63;
  const int la = lane & 15, quad = lane >> 4;
  const int iw = wave & 3, jw = wave >> 2;
  const int cb = wave * 32;

  __shared__ unsigned short pa[2][64 * 72];   // P bf16 [i][j], dbuf
  __shared__ unsigned short st[32 * 520];     // saT staging (half tile)
  __shared__ float l_lds[64];
  if (t < 64) l_lds[t] = 0.f;

  const unsigned short* qTb = qT + (size_t)b * N_ * CI_;
  const unsigned short* kTb = kT + (size_t)b * N_ * CI_;
  const unsigned short* vb  = vbf + (size_t)b * C_ * N_;

  // Q A-frags, register-resident (one 16-row i-subtile per wave)
  v8s qf[8];
  {
    const unsigned short* qrow = qTb + (size_t)(i0 + iw * 16 + la) * CI_ + quad * 8;
#pragma unroll
    for (int s = 0; s < 8; ++s) qf[s] = ld8(qrow + s * 32);
  }

  v4f acc[2][4];
#pragma unroll
  for (int ct = 0; ct < 2; ++ct)
#pragma unroll
    for (int it = 0; it < 4; ++it) acc[ct][it] = (v4f){0.f, 0.f, 0.f, 0.f};
  float lsum[4] = {0.f, 0.f, 0.f, 0.f};

  unsigned voff0 = (unsigned)(cb + la) * N_;
  unsigned voff1 = (unsigned)(cb + 16 + la) * N_;

  int buf = 0;
  for (int j0 = 0; j0 < N_; j0 += 64) {
    // ---- S = Q K^T for this wave's 16x16 subtile ----
    const unsigned short* krow = kTb + (size_t)(j0 + jw * 16 + la) * CI_ + quad * 8;
    v4f s = (v4f){0.f, 0.f, 0.f, 0.f};
#pragma unroll
    for (int sh = 0; sh < 8; ++sh) s = mfma16(qf[sh], ld8(krow + sh * 32), s);
    // ---- P = exp(S*scale - shift) ----
#pragma unroll
    for (int r = 0; r < 4; ++r) {
      float p = __expf(s[r] * SCALE_PAM - SHIFT_PAM);
      lsum[r] += p;
      pa[buf][(iw * 16 + quad * 4 + r) * 72 + jw * 16 + la] = f2bf(p);
    }
    __syncthreads();
    // ---- PV: acc[c][i] += V[c][j] P^T[j][i] ----
    v8s vf00 = ld8(&vb[voff0 + j0 + quad * 8]);
    v8s vf01 = ld8(&vb[voff0 + j0 + 32 + quad * 8]);
    v8s vf10 = ld8(&vb[voff1 + j0 + quad * 8]);
    v8s vf11 = ld8(&vb[voff1 + j0 + 32 + quad * 8]);
#pragma unroll
    for (int it = 0; it < 4; ++it) {
      v8s pf0; *(int4*)&pf0 = *(const int4*)&pa[buf][(it * 16 + la) * 72 + quad * 8];
      acc[0][it] = mfma16(vf00, pf0, acc[0][it]);
      acc[1][it] = mfma16(vf10, pf0, acc[1][it]);
      v8s pf1; *(int4*)&pf1 = *(const int4*)&pa[buf][(it * 16 + la) * 72 + 32 + quad * 8];
      acc[0][it] = mfma16(vf01, pf1, acc[0][it]);
      acc[1][it] = mfma16(vf11, pf1, acc[1][it]);
    }
    buf ^= 1;
  }

  // ---- reduce l per i-row (sum over j: la lanes within quad, then 4 jw waves) ----
#pragma unroll
  for (int r = 0; r < 4; ++r) {
    float v = lsum[r];
    v += __shfl_xor(v, 1); v += __shfl_xor(v, 2);
    v += __shfl_xor(v, 4); v += __shfl_xor(v, 8);
    if (la == 0) atomicAdd(&l_lds[iw * 16 + quad * 4 + r], v);
  }
  __syncthreads();

  const float gpv = gamma_pam[0];
  float linv[4];
#pragma unroll
  for (int it = 0; it < 4; ++it)
    linv[it] = 1.0f / (l_lds[it * 16 + la] * (float)N_);

  // ---- epilogue in 2 halves (it {0,1}, then {2,3}) to keep LDS <= 64KB ----
#pragma unroll
  for (int half = 0; half < 2; ++half) {
#pragma unroll
    for (int it2 = 0; it2 < 2; ++it2) {
      const int it = half * 2 + it2;
      const int nl = it * 16 + la;        // row in [0,64)
      const int nlh = it2 * 16 + la;      // row within half [0,32)
#pragma unroll
      for (int ct = 0; ct < 2; ++ct)
#pragma unroll
        for (int r = 0; r < 4; ++r) {
          int c = cb + ct * 16 + quad * 4 + r;
          size_t gi = ((size_t)b * C_ + c) * N_ + i0 + nl;
          float sv = tanhf(fmaf(gpv, acc[ct][it][r] * linv[it], x[gi]));
          unsigned short us = f2bf(sv);
          sabf[gi] = us;
          st[nlh * 520 + ((c + nlh * 32) & 511)] = us;
        }
    }
    __syncthreads();
    {
      const int nl2 = t >> 5, l5 = t & 31;
      unsigned short* dst = saT + ((size_t)b * N_ + i0 + half * 32 + nl2) * C_;
#pragma unroll
      for (int chunk = 0; chunk < 2; ++chunk) {
        int c0s = chunk * 256 + l5 * 8;
        int csw = (c0s + nl2 * 32) & 511;
        *(int4*)&dst[c0s] = *(int4*)&st[nl2 * 520 + csw];
      }
    }
    __syncthreads();
  }
}

// ---------------------------------------------------------------------------
// K3: CAM gram via MFMA, K-split 4. e_part[ks][b][c][d] = scale * sum sa_c sa_d
// ---------------------------------------------------------------------------
__global__ __launch_bounds__(256) void k_cam_e(const unsigned short* __restrict__ sabf,
                                               float* __restrict__ e_part) {
  const int b = blockIdx.z, ks = blockIdx.y;
  const int c0 = (blockIdx.x & 7) * 64, d0 = (blockIdx.x >> 3) * 64;
  const int t = threadIdx.x, wave = t >> 6, lane = t & 63;
  const int la = lane & 15, quad = lane >> 4;
  const int cw = wave & 1, dw = wave >> 1;
  const unsigned short* sb = sabf + (size_t)b * C_ * N_;

  v4f acc[2][2];
#pragma unroll
  for (int i = 0; i < 2; ++i)
#pragma unroll
    for (int j = 0; j < 2; ++j) acc[i][j] = (v4f){0.f, 0.f, 0.f, 0.f};

  const size_t ar0 = (size_t)(c0 + cw * 32 + la) * N_;
  const size_t br0 = (size_t)(d0 + dw * 32 + la) * N_;
#pragma unroll 4
  for (int s = 0; s < 32; ++s) {
    const int kof = ks * 1024 + s * 32 + quad * 8;
    v8s a0 = ld8(&sb[ar0 + kof]);
    v8s a1 = ld8(&sb[ar0 + (size_t)16 * N_ + kof]);
    v8s b0 = ld8(&sb[br0 + kof]);
    v8s b1 = ld8(&sb[br0 + (size_t)16 * N_ + kof]);
    acc[0][0] = mfma16(a0, b0, acc[0][0]);
    acc[0][1] = mfma16(a0, b1, acc[0][1]);
    acc[1][0] = mfma16(a1, b0, acc[1][0]);
    acc[1][1] = mfma16(a1, b1, acc[1][1]);
  }
  float* ep = e_part + ((size_t)(ks * B_ + b)) * C_ * C_;
#pragma unroll
  for (int i = 0; i < 2; ++i)
#pragma unroll
    for (int j = 0; j < 2; ++j)
#pragma unroll
      for (int r = 0; r < 4; ++r) {
        int c = c0 + cw * 32 + i * 16 + quad * 4 + r;
        int d = d0 + dw * 32 + j * 16 + la;
        ep[(size_t)c * C_ + d] = acc[i][j][r] * SCALE_CAM;
      }
}

// ---------------------------------------------------------------------------
// K4: CAM softmax (min-trick), sums 4 K-split parts, writes attn bf16 (/C folded).
// ---------------------------------------------------------------------------
__global__ __launch_bounds__(64) void k_cam_softmax(const float* __restrict__ e_part,
                                                    unsigned short* __restrict__ attnb) {
  const int c = blockIdx.x, b = blockIdx.y, lane = threadIdx.x;
  size_t roff = ((size_t)b * C_ + c) * C_;
  float vals[8];
#pragma unroll
  for (int r = 0; r < 8; ++r) {
    int d = lane + r * 64;
    float s = 0.f;
#pragma unroll
    for (int p = 0; p < 4; ++p) s += e_part[(size_t)(p * B_) * C_ * C_ + roff + d];
    vals[r] = s;
  }
  float mn = vals[0];
#pragma unroll
  for (int r = 1; r < 8; ++r) mn = fminf(mn, vals[r]);
#pragma unroll
  for (int m = 32; m >= 1; m >>= 1) mn = fminf(mn, __shfl_xor(mn, m));
  float sum = 0.f;
#pragma unroll
  for (int r = 0; r < 8; ++r) { vals[r] = __expf(mn - vals[r]); sum += vals[r]; }
#pragma unroll
  for (int m = 32; m >= 1; m >>= 1) sum += __shfl_xor(sum, m);
  float sc = (1.0f / (float)C_) / sum;
#pragma unroll
  for (int r = 0; r < 8; ++r) attnb[roff + lane + r * 64] = f2bf(vals[r] * sc);
}

// ---------------------------------------------------------------------------
// K5: out = gamma_cam * (attn @ sa) + sa.  128c x 128n tile, 512 thr.
// A = attn bf16 [c][d], B = saT [n][d]; residual from sabf (bf16).
// ---------------------------------------------------------------------------
__global__ __launch_bounds__(512, 4) void k_cam_out(
    const unsigned short* __restrict__ attnb, const unsigned short* __restrict__ saT,
    const unsigned short* __restrict__ sabf, const float* __restrict__ gamma_cam,
    float* __restrict__ out) {
  const int b = blockIdx.z, c0 = blockIdx.y * 128, n0 = blockIdx.x * 128;
  const int t = threadIdx.x, wave = t >> 6, lane = t & 63;
  const int la = lane & 15, quad = lane >> 4;
  const int cw = wave & 1, nw = wave >> 1;
  const unsigned short* ab = attnb + (size_t)b * C_ * C_;
  const unsigned short* sTb = saT + (size_t)b * N_ * C_;

  v4f acc[4][2];
#pragma unroll
  for (int i = 0; i < 4; ++i)
#pragma unroll
    for (int j = 0; j < 2; ++j) acc[i][j] = (v4f){0.f, 0.f, 0.f, 0.f};

  unsigned ar[4], br[2];
#pragma unroll
  for (int ci = 0; ci < 4; ++ci) ar[ci] = (unsigned)(c0 + cw * 64 + ci * 16 + la) * 512u;
#pragma unroll
  for (int nj = 0; nj < 2; ++nj) br[nj] = (unsigned)(n0 + nw * 32 + nj * 16 + la) * 512u;

#pragma unroll 4
  for (int s = 0; s < 16; ++s) {
    const int kof = s * 32 + quad * 8;
    v8s b0 = ld8(&sTb[br[0] + kof]);
    v8s b1 = ld8(&sTb[br[1] + kof]);
#pragma unroll
    for (int ci = 0; ci < 4; ++ci) {
      v8s a = ld8(&ab[ar[ci] + kof]);
      acc[ci][0] = mfma16(a, b0, acc[ci][0]);
      acc[ci][1] = mfma16(a, b1, acc[ci][1]);
    }
  }
  const float gc = gamma_cam[0];
#pragma unroll
  for (int ci = 0; ci < 4; ++ci)
#pragma unroll
    for (int nj = 0; nj < 2; ++nj)
#pragma unroll
      for (int r = 0; r < 4; ++r) {
        int c = c0 + cw * 64 + ci * 16 + quad * 4 + r;
        int n = n0 + nw * 32 + nj * 16 + la;
        size_t gi = ((size_t)b * C_ + c) * N_ + n;
        out[gi] = fmaf(gc, acc[ci][nj][r], bf2f(sabf[gi]));
      }
}

// ---------------------------------------------------------------------------
extern "C" void kernel_launch(void* const* d_in, const int* in_sizes, int n_in,
                              void* d_out, int out_size, void* d_ws, size_t ws_size,
                              hipStream_t stream) {
  const float* x  = (const float*)d_in[0];
  const float* wq = (const float*)d_in[1];
  const float* bq = (const float*)d_in[2];
  const float* wk = (const float*)d_in[3];
  const float* bk = (const float*)d_in[4];
  const float* wv = (const float*)d_in[5];
  const float* bv = (const float*)d_in[6];
  const float* gp = (const float*)d_in[7];
  const float* gc = (const float*)d_in[8];
  float* out = (float*)d_out;

  char* ws = (char*)d_ws;
  unsigned short* qT   = (unsigned short*)(ws);               // 8.39 MB
  unsigned short* kT   = (unsigned short*)(ws + 8388608);     // 8.39 MB
  unsigned short* vbf  = (unsigned short*)(ws + 16777216);    // 16.78 MB
  unsigned short* xT   = (unsigned short*)(ws + 33554432);    // 16.78 MB
  unsigned short* wb   = (unsigned short*)(ws + 50331648);    // 1.05 MB
  unsigned short* sabf = (unsigned short*)(ws + 51380224);    // 16.78 MB
  unsigned short* saT  = (unsigned short*)(ws + 68157440);    // 16.78 MB
  float*          ep   = (float*)(ws + 84934656);             // 16.78 MB
  unsigned short* atb  = (unsigned short*)(ws + 101711872);   // 2.10 MB
  // total ~104 MB

  k_xT<<<dim3(64, 8, B_), 256, 0, stream>>>(x, xT);
  k_wb<<<dim3(512), 256, 0, stream>>>(wq, wk, wv, wb);
  k_qkv<<<dim3(32, 8, B_), 512, 0, stream>>>(wb, xT, bq, bk, bv, qT, kT, vbf);
  k_pam<<<dim3(64, B_), 1024, 0, stream>>>(qT, kT, vbf, x, gp, sabf, saT);
  k_cam_e<<<dim3(64, 4, B_), 256, 0, stream>>>(sabf, ep);
  k_cam_softmax<<<dim3(C_, B_), 64, 0, stream>>>(ep, atb);
  k_cam_out<<<dim3(32, 4, B_), 512, 0, stream>>>(atb, saT, sabf, gc, out);
}